// Round 3
// baseline (74.153 us; speedup 1.0000x reference)
//
#include <hip/hip_runtime.h>
#include <hip/hip_cooperative_groups.h>
#include <math.h>

namespace cg = cooperative_groups;

#define NP 256      // ids_per_batch
#define NK 16       // imgs_per_id
#define ND 2048     // feature_dim
#define MARGIN 10.0f
#define EPSV 1e-12f

typedef short bf16x8 __attribute__((ext_vector_type(8)));   // 8 bf16 (4 VGPRs)
typedef float f32x4 __attribute__((ext_vector_type(4)));    // MFMA C/D

static __device__ __forceinline__ unsigned short f2bf(float f) {
  unsigned u = __float_as_uint(f);
  return (unsigned short)((u + 0x7fffu + ((u >> 16) & 1u)) >> 16);  // RNE
}

// One cooperative kernel, 256 blocks x 512 threads (1 block/CU, 8 waves/CU).
// Phase 1: block p -> center_p (bf16), cc_p, intra_max_p, inter init +inf.
// Phase 2: block b -> 16x16 G-tile (pi=b>>4, qi=b&15), 8 waves split K=2048,
//          LDS reduce, fused inter_min atomicMin epilogue.
// Phase 3: block 0 -> loss.
__global__ __launch_bounds__(512, 2) void k_fused(
    const float* __restrict__ F, unsigned short* __restrict__ Cb,
    float* __restrict__ cc, float* __restrict__ out) {
  const int b = blockIdx.x;
  const int t = threadIdx.x;
  const int wave = t >> 6, lane = t & 63;

  __shared__ float red[8][NK + 1];
  __shared__ float red2[8][256];
  __shared__ float red3[8];

  // ---------------- Phase 1: per-class center + intra_max ----------------
  {
    const int p = b;
    const int d = t * 4;
    float4 x[NK];
#pragma unroll
    for (int k = 0; k < NK; ++k)
      x[k] = *reinterpret_cast<const float4*>(
          &F[((size_t)(p * NK + k)) * ND + d]);
    float4 c;
    c.x = c.y = c.z = c.w = 0.f;
#pragma unroll
    for (int k = 0; k < NK; ++k) {
      c.x += x[k].x; c.y += x[k].y; c.z += x[k].z; c.w += x[k].w;
    }
    const float inv = 1.0f / 16.0f;
    c.x *= inv; c.y *= inv; c.z *= inv; c.w *= inv;

    ushort4 cb;
    cb.x = f2bf(c.x); cb.y = f2bf(c.y); cb.z = f2bf(c.z); cb.w = f2bf(c.w);
    *reinterpret_cast<ushort4*>(&Cb[(size_t)p * ND + d]) = cb;

    float ccp = c.x * c.x + c.y * c.y + c.z * c.z + c.w * c.w;

    float acc[NK];
#pragma unroll
    for (int k = 0; k < NK; ++k) {
      float dx = x[k].x - c.x, dy = x[k].y - c.y;
      float dz = x[k].z - c.z, dw = x[k].w - c.w;
      acc[k] = dx * dx + dy * dy + dz * dz + dw * dw;
    }
#pragma unroll
    for (int k = 0; k < NK; ++k) {
      float v = acc[k];
#pragma unroll
      for (int m = 32; m > 0; m >>= 1) v += __shfl_xor(v, m);
      acc[k] = v;
    }
    {
      float v = ccp;
#pragma unroll
      for (int m = 32; m > 0; m >>= 1) v += __shfl_xor(v, m);
      ccp = v;
    }
    if (lane == 0) {
#pragma unroll
      for (int k = 0; k < NK; ++k) red[wave][k] = acc[k];
      red[wave][NK] = ccp;
    }
    __syncthreads();
    if (t == 0) {
      float m = 0.f;
#pragma unroll
      for (int k = 0; k < NK; ++k) {
        float s = 0.f;
#pragma unroll
        for (int w = 0; w < 8; ++w) s += red[w][k];
        m = fmaxf(m, sqrtf(fmaxf(s, EPSV)));
      }
      out[1 + p] = m;  // intra_max
      float s = 0.f;
#pragma unroll
      for (int w = 0; w < 8; ++w) s += red[w][NK];
      cc[p] = s;
      reinterpret_cast<int*>(out)[1 + NP + p] = 0x7f800000;  // +inf init
    }
  }

  cg::this_grid().sync();

  // ---------------- Phase 2: 16x16 G-tile, split-K=8, fused inter ----------
  {
    const int pi = b >> 4, qi = b & 15;
    const int lr = lane & 15;        // A row / B col within tile
    const int kg = (lane >> 4) * 8;  // k-base within 32-chunk
    const unsigned short* ap =
        &Cb[(size_t)(pi * 16 + lr) * ND + wave * 256 + kg];
    const unsigned short* bp =
        &Cb[(size_t)(qi * 16 + lr) * ND + wave * 256 + kg];
    f32x4 acc = {0.f, 0.f, 0.f, 0.f};
#pragma unroll
    for (int i = 0; i < 8; ++i) {
      bf16x8 a = *reinterpret_cast<const bf16x8*>(ap + i * 32);
      bf16x8 bb = *reinterpret_cast<const bf16x8*>(bp + i * 32);
      acc = __builtin_amdgcn_mfma_f32_16x16x32_bf16(a, bb, acc, 0, 0, 0);
    }
    // C/D layout: col = lane&15, row = (lane>>4)*4 + reg
#pragma unroll
    for (int r = 0; r < 4; ++r) red2[wave][lane * 4 + r] = acc[r];
    __syncthreads();
    if (t < 256) {
      float g = 0.f;
#pragma unroll
      for (int w = 0; w < 8; ++w) g += red2[w][t];
      // t = lane*4 + r with lane = t>>2: row = (lane>>4)*4 + r, col = lane&15
      const int row = ((t >> 6) & 3) * 4 + (t & 3);
      const int col = (t >> 2) & 15;
      const int p = pi * 16 + row, q = qi * 16 + col;
      const float cd2 = cc[p] + cc[q] - 2.0f * g;
      float cd = (p == q) ? INFINITY : sqrtf(fmaxf(cd2, EPSV));
      // min over the 16 cols of this row: col lives in t bits 2..5
#pragma unroll
      for (int m = 4; m <= 32; m <<= 1) cd = fminf(cd, __shfl_xor(cd, m));
      if (col == 0)
        atomicMin(reinterpret_cast<int*>(out) + 1 + NP + p,
                  __float_as_int(cd));
    }
  }

  cg::this_grid().sync();

  // ---------------- Phase 3: loss (block 0) ----------------
  if (b == 0) {
    float v = 0.f;
    if (t < NP) v = fmaxf(out[1 + t] - out[1 + NP + t] + MARGIN, 0.f);
#pragma unroll
    for (int m = 32; m > 0; m >>= 1) v += __shfl_xor(v, m);
    if (lane == 0) red3[wave] = v;
    __syncthreads();
    if (t == 0) {
      float s = 0.f;
#pragma unroll
      for (int w = 0; w < 8; ++w) s += red3[w];
      out[0] = s / (float)NP;
    }
  }
}

// ---------------------------------------------------------------------------
extern "C" void kernel_launch(void* const* d_in, const int* in_sizes, int n_in,
                              void* d_out, int out_size, void* d_ws,
                              size_t ws_size, hipStream_t stream) {
  const float* F = (const float*)d_in[0];  // features [4096, 2048] fp32
  float* out = (float*)d_out;              // [513]: loss, intra_max, inter_min

  unsigned short* Cb = (unsigned short*)d_ws;  // 256*2048 bf16 (1 MB)
  float* cc = (float*)(Cb + (size_t)NP * ND);  // 256 fp32

  void* args[4] = {(void*)&F, (void*)&Cb, (void*)&cc, (void*)&out};
  hipLaunchCooperativeKernel((const void*)k_fused, dim3(NP), dim3(512), args,
                             0, stream);
}

// Round 4
// 34.414 us; speedup vs baseline: 2.1547x; 2.1547x over previous
//
#include <hip/hip_runtime.h>
#include <math.h>

#define NP 256      // ids_per_batch
#define NK 16       // imgs_per_id
#define ND 2048     // feature_dim
#define MARGIN 10.0f
#define EPSV 1e-12f
#define NBLK_B 64   // blocks in kernel B (4 waves each -> 256 tiles)

typedef short bf16x8 __attribute__((ext_vector_type(8)));   // 8 bf16 (4 VGPRs)
typedef float f32x4 __attribute__((ext_vector_type(4)));    // MFMA C/D

static __device__ __forceinline__ unsigned short f2bf(float f) {
  unsigned u = __float_as_uint(f);
  return (unsigned short)((u + 0x7fffu + ((u >> 16) & 1u)) >> 16);  // RNE
}

// ---------------------------------------------------------------------------
// A: block p -> center_p (bf16), cc_p, intra_max_p; init inter=+inf; zero
// the ticket counter. 512 threads, each owns one float4 column slice.
// x[16] pinned live in VGPRs (asm) so the compiler can't re-load from global.
// ---------------------------------------------------------------------------
__global__ __launch_bounds__(512) void k_center_intra(
    const float* __restrict__ F, unsigned short* __restrict__ Cb,
    float* __restrict__ cc, int* __restrict__ ticket,
    float* __restrict__ out) {
  const int p = blockIdx.x;
  const int t = threadIdx.x;
  const int wave = t >> 6, lane = t & 63;
  const int d = t * 4;

  float4 x[NK];
#pragma unroll
  for (int k = 0; k < NK; ++k)
    x[k] = *reinterpret_cast<const float4*>(&F[((size_t)(p * NK + k)) * ND + d]);
#pragma unroll
  for (int k = 0; k < NK; ++k)
    asm volatile("" : "+v"(x[k].x), "+v"(x[k].y), "+v"(x[k].z), "+v"(x[k].w));

  float4 c;
  c.x = c.y = c.z = c.w = 0.f;
#pragma unroll
  for (int k = 0; k < NK; ++k) {
    c.x += x[k].x; c.y += x[k].y; c.z += x[k].z; c.w += x[k].w;
  }
  const float inv = 1.0f / 16.0f;
  c.x *= inv; c.y *= inv; c.z *= inv; c.w *= inv;

  ushort4 cb;
  cb.x = f2bf(c.x); cb.y = f2bf(c.y); cb.z = f2bf(c.z); cb.w = f2bf(c.w);
  *reinterpret_cast<ushort4*>(&Cb[(size_t)p * ND + d]) = cb;

  float ccp = c.x * c.x + c.y * c.y + c.z * c.z + c.w * c.w;

  float acc[NK];
#pragma unroll
  for (int k = 0; k < NK; ++k) {
    float dx = x[k].x - c.x, dy = x[k].y - c.y;
    float dz = x[k].z - c.z, dw = x[k].w - c.w;
    acc[k] = dx * dx + dy * dy + dz * dz + dw * dw;
  }

#pragma unroll
  for (int k = 0; k < NK; ++k) {
    float v = acc[k];
#pragma unroll
    for (int m = 32; m > 0; m >>= 1) v += __shfl_xor(v, m);
    acc[k] = v;
  }
  {
    float v = ccp;
#pragma unroll
    for (int m = 32; m > 0; m >>= 1) v += __shfl_xor(v, m);
    ccp = v;
  }

  __shared__ float red[8][NK + 1];
  if (lane == 0) {
#pragma unroll
    for (int k = 0; k < NK; ++k) red[wave][k] = acc[k];
    red[wave][NK] = ccp;
  }
  __syncthreads();
  if (t == 0) {
    float m = 0.f;
#pragma unroll
    for (int k = 0; k < NK; ++k) {
      float s = 0.f;
#pragma unroll
      for (int w = 0; w < 8; ++w) s += red[w][k];
      m = fmaxf(m, sqrtf(fmaxf(s, EPSV)));
    }
    out[1 + p] = m;  // intra_max
    float s = 0.f;
#pragma unroll
    for (int w = 0; w < 8; ++w) s += red[w][NK];
    cc[p] = s;
    reinterpret_cast<int*>(out)[1 + NP + p] = 0x7f800000;  // +inf
    if (p == 0) atomicExch(ticket, 0);
  }
}

// ---------------------------------------------------------------------------
// B: 64 blocks x 4 waves; wave -> one 16x16 G-tile over full K=2048 (MFMA,
// 4 interleaved acc chains). Fused inter_min atomicMin; last block computes
// the loss after a threadfence+ticket handoff.
// ---------------------------------------------------------------------------
__global__ __launch_bounds__(256) void k_pair_loss(
    const unsigned short* __restrict__ Cb, const float* __restrict__ cc,
    int* __restrict__ ticket, float* __restrict__ out) {
  const int t = threadIdx.x;
  const int wave = t >> 6, lane = t & 63;
  const int tile = blockIdx.x * 4 + wave;  // 0..255
  const int pi = tile >> 4, qi = tile & 15;
  const int lr = lane & 15;
  const int kg = (lane >> 4) * 8;

  const unsigned short* ap = &Cb[(size_t)(pi * 16 + lr) * ND + kg];
  const unsigned short* bp = &Cb[(size_t)(qi * 16 + lr) * ND + kg];

  f32x4 a0 = {0.f, 0.f, 0.f, 0.f}, a1 = a0, a2 = a0, a3 = a0;
#pragma unroll
  for (int i = 0; i < 16; ++i) {
    bf16x8 av0 = *reinterpret_cast<const bf16x8*>(ap + i * 128);
    bf16x8 bv0 = *reinterpret_cast<const bf16x8*>(bp + i * 128);
    bf16x8 av1 = *reinterpret_cast<const bf16x8*>(ap + i * 128 + 32);
    bf16x8 bv1 = *reinterpret_cast<const bf16x8*>(bp + i * 128 + 32);
    bf16x8 av2 = *reinterpret_cast<const bf16x8*>(ap + i * 128 + 64);
    bf16x8 bv2 = *reinterpret_cast<const bf16x8*>(bp + i * 128 + 64);
    bf16x8 av3 = *reinterpret_cast<const bf16x8*>(ap + i * 128 + 96);
    bf16x8 bv3 = *reinterpret_cast<const bf16x8*>(bp + i * 128 + 96);
    a0 = __builtin_amdgcn_mfma_f32_16x16x32_bf16(av0, bv0, a0, 0, 0, 0);
    a1 = __builtin_amdgcn_mfma_f32_16x16x32_bf16(av1, bv1, a1, 0, 0, 0);
    a2 = __builtin_amdgcn_mfma_f32_16x16x32_bf16(av2, bv2, a2, 0, 0, 0);
    a3 = __builtin_amdgcn_mfma_f32_16x16x32_bf16(av3, bv3, a3, 0, 0, 0);
  }
  f32x4 acc = a0 + a1 + a2 + a3;

  // C/D layout: col = lane&15, row = (lane>>4)*4 + reg
  const int rbase = (lane >> 4) * 4;
  const int qg = qi * 16 + lr;
  const float ccq = cc[qg];
  float cdm[4];
#pragma unroll
  for (int r = 0; r < 4; ++r) {
    const int pg = pi * 16 + rbase + r;
    const float cd2 = cc[pg] + ccq - 2.0f * acc[r];
    cdm[r] = (pg == qg) ? INFINITY : sqrtf(fmaxf(cd2, EPSV));
  }
#pragma unroll
  for (int r = 0; r < 4; ++r) {
#pragma unroll
    for (int m = 8; m > 0; m >>= 1) cdm[r] = fminf(cdm[r], __shfl_xor(cdm[r], m));
  }
  if (lr == 0) {
#pragma unroll
    for (int r = 0; r < 4; ++r)
      atomicMin(reinterpret_cast<int*>(out) + 1 + NP + pi * 16 + rbase + r,
                __float_as_int(cdm[r]));
  }

  // ---- last-block loss ----
  __syncthreads();
  __threadfence();
  __shared__ int my_ticket;
  if (t == 0) my_ticket = atomicAdd(ticket, 1);
  __syncthreads();
  if (my_ticket == NBLK_B - 1) {
    const float im = out[1 + t];  // written by kernel A
    const int bits = atomicOr(reinterpret_cast<int*>(out) + 1 + NP + t, 0);
    const float in_ = __int_as_float(bits);
    float v = fmaxf(im - in_ + MARGIN, 0.f);
#pragma unroll
    for (int m = 32; m > 0; m >>= 1) v += __shfl_xor(v, m);
    __shared__ float red[4];
    if (lane == 0) red[wave] = v;
    __syncthreads();
    if (t == 0) out[0] = (red[0] + red[1] + red[2] + red[3]) / (float)NP;
  }
}

// ---------------------------------------------------------------------------
extern "C" void kernel_launch(void* const* d_in, const int* in_sizes, int n_in,
                              void* d_out, int out_size, void* d_ws,
                              size_t ws_size, hipStream_t stream) {
  const float* F = (const float*)d_in[0];  // features [4096, 2048] fp32
  float* out = (float*)d_out;              // [513]: loss, intra_max, inter_min

  unsigned short* Cb = (unsigned short*)d_ws;  // 256*2048 bf16 (1 MB)
  float* cc = (float*)(Cb + (size_t)NP * ND);  // 256 fp32
  int* ticket = (int*)(cc + NP);               // 1 int

  k_center_intra<<<NP, 512, 0, stream>>>(F, Cb, cc, ticket, out);
  k_pair_loss<<<NBLK_B, 256, 0, stream>>>(Cb, cc, ticket, out);
}